// Round 5
// baseline (274.624 us; speedup 1.0000x reference)
//
#include <hip/hip_runtime.h>

#define N 4096
#define D 512
#define BM 32                   // qrows per block
#define BN 32                   // keys per tile
#define KS 8                    // key-split
#define CHUNK (N / KS)          // 512 keys per block
#define NT (CHUNK / BN)         // 16 tiles per block
#define NKT (N / 64)            // 64 prep parent tiles (64 keys each)
#define FRAG_SH 512             // shorts per 16x32 fragment (1 KB)
#define TILE64_SH (64 * FRAG_SH)
#define PB_W 40                 // Pb row stride in shorts (80 B: 16B-aligned rows)

typedef __attribute__((ext_vector_type(8))) short short8;
typedef __attribute__((ext_vector_type(4))) float f32x4;

__device__ __forceinline__ unsigned short f2bf(float f) {
    unsigned int u = __float_as_uint(f);
    u = (u + 0x7FFFu + ((u >> 16) & 1u)) >> 16;
    return (unsigned short)u;
}
__device__ __forceinline__ unsigned short f2bf_rn(float f) {
    return (unsigned short)((__float_as_uint(f) + 0x8000u) >> 16);
}
__device__ __forceinline__ void load_lds16(const unsigned short* g, unsigned short* l) {
    __builtin_amdgcn_global_load_lds(
        (const __attribute__((address_space(1))) void*)g,
        (__attribute__((address_space(3))) void*)l, 16, 0, 0);
}

// Fused prep: blocks [0,2048) cast+scale Q; blocks [2048, 2048+128) build
// fragment-linear Kblk (QK^T B-frags) and Vblk (PV B-frags) from hist.
__global__ __launch_bounds__(256) void prep_all(const float* __restrict__ q,
                                                const float* __restrict__ hist,
                                                unsigned short* __restrict__ Qbf,
                                                unsigned short* __restrict__ Kblk,
                                                unsigned short* __restrict__ Vblk) {
    __shared__ unsigned short tile[32 * 512];
    const int bx = blockIdx.x;
    const int tid = threadIdx.x;
    if (bx < 2048) {
        int i = (bx * 256 + tid) * 4;
        const float s = 0.04419417382415922f;   // 1/sqrt(512) folded into Q
        float4 v = *(const float4*)(q + i);
        ushort4 o;
        o.x = f2bf(v.x * s); o.y = f2bf(v.y * s); o.z = f2bf(v.z * s); o.w = f2bf(v.w * s);
        *(ushort4*)(Qbf + i) = o;
        return;
    }
    const int b = bx - 2048;
    const int t = b >> 1;       // parent 64-key tile
    const int h = b & 1;        // 32-key half
    #pragma unroll
    for (int k = 0; k < 16; ++k) {
        int idx = tid + k * 256;
        int row = idx >> 7;
        int c4  = (idx & 127) << 2;
        float4 v = *(const float4*)(hist + (size_t)(t * 64 + h * 32 + row) * D + c4);
        ushort4 o;
        o.x = f2bf(v.x); o.y = f2bf(v.y); o.z = f2bf(v.z); o.w = f2bf(v.w);
        *(ushort4*)(tile + row * 512 + c4) = o;
    }
    __syncthreads();
    // Kblk frags f = kb*4 + wc, wc in {2h, 2h+1}: B[n=key wc*16+l16][k=d kb*32+q4*8+j]
    #pragma unroll
    for (int k = 0; k < 8; ++k) {
        int s = tid + k * 256;
        int fl = s >> 6, lane = s & 63;
        int kb = fl >> 1, wcl = fl & 1, wc = 2 * h + wcl;
        int l16 = lane & 15, q4 = lane >> 4;
        short8 v = *(const short8*)(tile + (wcl * 16 + l16) * 512 + kb * 32 + q4 * 8);
        *(short8*)(Kblk + (size_t)t * TILE64_SH + (size_t)(kb * 4 + wc) * FRAG_SH + lane * 8) = v;
    }
    // Vblk frags g = ks*32 + nb, ks == h: B[n=dcol nb*16+l16][k=key ks*32+q4*8+j]
    #pragma unroll
    for (int k = 0; k < 8; ++k) {
        int s = tid + k * 256;
        int nb = s >> 6, lane = s & 63;
        int g = h * 32 + nb;
        int l16 = lane & 15, q4 = lane >> 4;
        unsigned short tmp[8];
        #pragma unroll
        for (int j = 0; j < 8; ++j)
            tmp[j] = tile[(q4 * 8 + j) * 512 + nb * 16 + l16];
        *(short8*)(Vblk + (size_t)t * TILE64_SH + (size_t)g * FRAG_SH + lane * 8) = *(const short8*)tmp;
    }
}

// Flash partial, m97-profile: 256 thr (4 waves), BM=32 qrows, BN=32 keys,
// LDS 34.6 KB + ~165 regs -> 3 blocks/CU (cross-block barrier overlap).
// Waves: wr=wv&1 (16-qrow strip); kc=wv>>1 (key-half in QK^T, dcol-half in PV).
// K tile staged via global_load_lds, single-buffered, staging issued after the
// P-barrier so it hides under PV. V B-frags straight from global Vblk (L2-hot).
__global__ __launch_bounds__(256, 3) void flash_kernel(
    const unsigned short* __restrict__ Qbf,
    const unsigned short* __restrict__ Kblk,
    const unsigned short* __restrict__ Vblk,
    const float* __restrict__ times,
    const float* __restrict__ w1,
    const float* __restrict__ b1,
    const float* __restrict__ w2,
    const float* __restrict__ b2,
    float* __restrict__ out,      // numerator accumulator (pre-zeroed)
    float* __restrict__ denom)    // [N] exp-sum accumulator (pre-zeroed)
{
    __shared__ unsigned short Ks[32 * FRAG_SH];   // 32 KB: 32 frags, frag-linear
    __shared__ unsigned short Pb[BM][PB_W];       // 2.5 KB: P, A-layout rows

    const int tid  = threadIdx.x;
    const int wv   = tid >> 6;
    const int lane = tid & 63;
    const int q4   = lane >> 4;
    const int l16  = lane & 15;
    const int wr   = wv & 1;
    const int kc   = wv >> 1;      // 0..1
    const int bx   = blockIdx.x;
    const int chunk = bx & 7;      // XCD-affine: chunk's 1MB K+V stays in that XCD's L2
    const int R0   = (bx >> 3) * BM;
    const int T0   = chunk * NT;   // base 32-key tile index

    // Q A-frags (pre-scaled): rows R0 + wr*16 + l16
    short8 qfrag[16];
    {
        const unsigned short* qp = Qbf + (size_t)(R0 + wr * 16 + l16) * D + q4 * 8;
        #pragma unroll
        for (int kb = 0; kb < 16; ++kb)
            qfrag[kb] = *(const short8*)(qp + kb * 32);
    }

    float tr[4];
    #pragma unroll
    for (int ri = 0; ri < 4; ++ri) tr[ri] = times[R0 + wr * 16 + q4 * 4 + ri];

    float w1v[8], b1v[8], w2v[8];
    #pragma unroll
    for (int k = 0; k < 8; ++k) { w1v[k] = w1[k]; b1v[k] = b1[k]; w2v[k] = w2[k]; }
    const float b2v = b2[0];
    bool fast = true;
    #pragma unroll
    for (int k = 0; k < 8; ++k) fast = fast && (b1v[k] == 0.0f);
    float C1 = 0.0f;
    #pragma unroll
    for (int k = 0; k < 8; ++k) C1 += w2v[k] * fmaxf(w1v[k], 0.0f);

    f32x4 of[16];
    #pragma unroll
    for (int dt = 0; dt < 16; ++dt) of[dt] = (f32x4){0.f, 0.f, 0.f, 0.f};
    float lacc[4] = {0.f, 0.f, 0.f, 0.f};

    // stage tile t32 into Ks: 32 frags; frag g=(kb,kh) <- parent frag kb*4+2h+kh
    #define STAGE(t32)                                                              \
        {                                                                           \
            const unsigned short* src = Kblk + (size_t)((t32) >> 1) * TILE64_SH;    \
            const int hh = ((t32) & 1) * 2;                                         \
            _Pragma("unroll")                                                       \
            for (int i = 0; i < 8; ++i) {                                           \
                int g = wv * 8 + i;                                                 \
                load_lds16(src + (size_t)((g >> 1) * 4 + hh + (g & 1)) * FRAG_SH + lane * 8, \
                           Ks + g * FRAG_SH + lane * 8);                            \
            }                                                                       \
        }

    STAGE(T0);
    __syncthreads();   // compiler drains vmcnt before barrier -> Ks ready

    for (int t = 0; t < NT; ++t) {
        const int t32 = T0 + t;
        const float tc = times[t32 * BN + kc * 16 + l16];   // issued early

        // ---- QK^T: S strip [16 qrows x 16 keys], B-frags conflict-free from Ks ----
        f32x4 c = {0, 0, 0, 0};
        #pragma unroll
        for (int kb = 0; kb < 16; ++kb) {
            short8 b = *(const short8*)(Ks + (kb * 2 + kc) * FRAG_SH + lane * 8);
            c = __builtin_amdgcn_mfma_f32_16x16x32_bf16(qfrag[kb], b, c, 0, 0, 0);
        }

        // ---- time weight (collapsed MLP) + exp; P -> LDS in A-layout rows ----
        #pragma unroll
        for (int ri = 0; ri < 4; ++ri) {
            float td = fabsf(tr[ri] - tc);
            float a = fmaf(td, C1, b2v);
            if (!fast) {
                a = b2v;
                #pragma unroll
                for (int k = 0; k < 8; ++k)
                    a += w2v[k] * fmaxf(fmaf(td, w1v[k], b1v[k]), 0.f);
            }
            float twt = __builtin_amdgcn_rcpf(1.0f + __expf(-a));
            float e = __expf(c[ri] * twt);   // 1/sqrt(D) pre-folded into Q
            lacc[ri] += e;
            Pb[wr * 16 + q4 * 4 + ri][kc * 16 + l16] = f2bf_rn(e);
        }
        __syncthreads();   // P visible; all Ks reads of tile t done

        // ---- stage next K tile: hides under PV, drained by the bottom barrier ----
        if (t + 1 < NT) STAGE(t32 + 1);

        // ---- PV: O strip [16 qrows x 256 dcols] += P . V, B-frags from global ----
        {
            short8 af = *(const short8*)(&Pb[wr * 16 + l16][q4 * 8]);
            const unsigned short* Vt = Vblk + (size_t)(t32 >> 1) * TILE64_SH
                                            + (size_t)((t32 & 1) * 32 + kc * 16) * FRAG_SH;
            #pragma unroll
            for (int dt = 0; dt < 16; ++dt) {
                short8 b = *(const short8*)(Vt + dt * FRAG_SH + lane * 8);
                of[dt] = __builtin_amdgcn_mfma_f32_16x16x32_bf16(af, b, of[dt], 0, 0, 0);
            }
        }
        __syncthreads();   // next tile's Ks staged (vmcnt drained); Pb readers done
    }

    // ---- partial denominator: reduce key dim (l16) via butterfly, one atomic ----
    #pragma unroll
    for (int ri = 0; ri < 4; ++ri) {
        float v = lacc[ri];
        v += __shfl_xor(v, 1);
        v += __shfl_xor(v, 2);
        v += __shfl_xor(v, 4);
        v += __shfl_xor(v, 8);
        if (l16 == 0) atomicAdd(denom + R0 + wr * 16 + q4 * 4 + ri, v);
    }

    // ---- partial numerator: coalesced fp32 atomics ----
    #pragma unroll
    for (int ri = 0; ri < 4; ++ri) {
        const int row = R0 + wr * 16 + q4 * 4 + ri;
        #pragma unroll
        for (int dt = 0; dt < 16; ++dt)
            atomicAdd(out + (size_t)row * D + kc * 256 + dt * 16 + l16, of[dt][ri]);
    }
    #undef STAGE
}

// out[i, :] /= denom[i]
__global__ void normalize_kernel(float* __restrict__ out, const float* __restrict__ denom) {
    int i = blockIdx.x * 256 + threadIdx.x;
    int row = i >> 7;
    float inv = 1.0f / denom[row];
    float4 v = ((const float4*)out)[i];
    v.x *= inv; v.y *= inv; v.z *= inv; v.w *= inv;
    ((float4*)out)[i] = v;
}

extern "C" void kernel_launch(void* const* d_in, const int* in_sizes, int n_in,
                              void* d_out, int out_size, void* d_ws, size_t ws_size,
                              hipStream_t stream) {
    const float* q     = (const float*)d_in[0];
    const float* hist  = (const float*)d_in[1];
    const float* times = (const float*)d_in[2];
    const float* w1    = (const float*)d_in[3];
    const float* b1    = (const float*)d_in[4];
    const float* w2    = (const float*)d_in[5];
    const float* b2    = (const float*)d_in[6];
    float* out = (float*)d_out;

    unsigned short* Qbf  = (unsigned short*)d_ws;         // 4 MB
    unsigned short* Kblk = Qbf + (size_t)N * D;           // 4 MB fragment-linear
    unsigned short* Vblk = Kblk + (size_t)N * D;          // 4 MB fragment-linear
    float* denom = (float*)(Vblk + (size_t)N * D);        // 16 KB

    hipMemsetAsync(out, 0, (size_t)N * D * sizeof(float), stream);
    hipMemsetAsync(denom, 0, (size_t)N * sizeof(float), stream);

    prep_all<<<2048 + NKT * 2, 256, 0, stream>>>(q, hist, Qbf, Kblk, Vblk);
    flash_kernel<<<(N / BM) * KS, 256, 0, stream>>>(
        Qbf, Kblk, Vblk, times, w1, b1, w2, b2, out, denom);
    normalize_kernel<<<(N * D / 4) / 256, 256, 0, stream>>>(out, denom);
}

// Round 6
// 201.711 us; speedup vs baseline: 1.3615x; 1.3615x over previous
//
#include <hip/hip_runtime.h>

#define N 4096
#define D 512
#define BM 64
#define BN 64
#define KS 4
#define CHUNK (N / KS)          // 1024 keys per block
#define NTILES (CHUNK / BN)     // 16 tiles per block
#define NKT (N / BN)            // 64 key tiles total
#define FRAG_SH 512             // shorts per 16x32 fragment (1 KB)
#define TILE_SH (64 * FRAG_SH)  // shorts per key tile (64 frags = 64 KB)
#define PB_W 72                 // Pb row stride (shorts)

typedef __attribute__((ext_vector_type(8))) short short8;
typedef __attribute__((ext_vector_type(4))) float f32x4;

__device__ __forceinline__ unsigned short f2bf(float f) {
    unsigned int u = __float_as_uint(f);
    u = (u + 0x7FFFu + ((u >> 16) & 1u)) >> 16;
    return (unsigned short)u;
}
__device__ __forceinline__ unsigned short f2bf_rn(float f) {
    return (unsigned short)((__float_as_uint(f) + 0x8000u) >> 16);
}
__device__ __forceinline__ void load_lds16(const unsigned short* g, unsigned short* l) {
    __builtin_amdgcn_global_load_lds(
        (const __attribute__((address_space(1))) void*)g,
        (__attribute__((address_space(3))) void*)l, 16, 0, 0);
}

// Q fp32 -> bf16, pre-scaled by 1/sqrt(D)
__global__ void prep_q(const float* __restrict__ in, unsigned short* __restrict__ out) {
    int i = (blockIdx.x * 256 + threadIdx.x) * 4;
    const float s = 0.04419417382415922f;
    float4 v = *(const float4*)(in + i);
    ushort4 o;
    o.x = f2bf(v.x * s); o.y = f2bf(v.y * s); o.z = f2bf(v.z * s); o.w = f2bf(v.w * s);
    *(ushort4*)(out + i) = o;
}

// K fp32 -> fragment-linear blocked layouts (QK^T B-frags / PV B-frags).
__global__ __launch_bounds__(256) void prep_kv(const float* __restrict__ K,
                                               unsigned short* __restrict__ Kblk,
                                               unsigned short* __restrict__ Vblk) {
    __shared__ unsigned short tile[32 * 512];   // 32 KB
    const int t = blockIdx.x >> 1;
    const int h = blockIdx.x & 1;
    const int tid = threadIdx.x;

    #pragma unroll
    for (int k = 0; k < 16; ++k) {
        int idx = tid + k * 256;
        int row = idx >> 7;
        int c4  = (idx & 127) << 2;
        float4 v = *(const float4*)(K + (size_t)(t * 64 + h * 32 + row) * D + c4);
        ushort4 o;
        o.x = f2bf(v.x); o.y = f2bf(v.y); o.z = f2bf(v.z); o.w = f2bf(v.w);
        *(ushort4*)(tile + row * 512 + c4) = o;
    }
    __syncthreads();

    #pragma unroll
    for (int k = 0; k < 8; ++k) {
        int s = tid + k * 256;
        int fl = s >> 6, lane = s & 63;
        int kb = fl >> 1, wcl = fl & 1, wc = 2 * h + wcl;
        int l16 = lane & 15, q4 = lane >> 4;
        short8 v = *(const short8*)(tile + (wcl * 16 + l16) * 512 + kb * 32 + q4 * 8);
        *(short8*)(Kblk + (size_t)t * TILE_SH + ((size_t)(kb * 4 + wc)) * FRAG_SH + lane * 8) = v;
    }
    #pragma unroll
    for (int k = 0; k < 8; ++k) {
        int s = tid + k * 256;
        int nb = s >> 6, lane = s & 63;
        int g = h * 32 + nb;
        int l16 = lane & 15, q4 = lane >> 4;
        unsigned short tmp[8];
        #pragma unroll
        for (int j = 0; j < 8; ++j)
            tmp[j] = tile[(q4 * 8 + j) * 512 + nb * 16 + l16];
        *(short8*)(Vblk + (size_t)t * TILE_SH + (size_t)g * FRAG_SH + lane * 8) = *(const short8*)tmp;
    }
}

// Flash-attention partial — identical loop structure to R4 (best measured).
// Epilogue: plain coalesced stores to per-chunk partial slabs (use_part=1),
// or legacy atomicAdd fallback if ws too small (use_part=0).
__global__ __launch_bounds__(512, 2) void flash_kernel(
    const unsigned short* __restrict__ Qbf,
    const unsigned short* __restrict__ Kblk,
    const unsigned short* __restrict__ Vblk,
    const float* __restrict__ times,
    const float* __restrict__ w1,
    const float* __restrict__ b1,
    const float* __restrict__ w2,
    const float* __restrict__ b2,
    float* __restrict__ onum,     // use_part: Opart[KS][N][D]; else out accumulator
    float* __restrict__ dden,     // use_part: dpart[KS][N];   else denom accumulator
    int use_part)
{
    extern __shared__ unsigned short smem[];
    unsigned short* Ks0 = smem;                       // 64 KB
    unsigned short* Ks1 = smem + TILE_SH;             // 64 KB
    unsigned short* Pb  = smem + 2 * TILE_SH;         // 64 x 72 shorts = 9 KB
    float* lred = (float*)(smem + 2 * TILE_SH + 64 * PB_W);  // [64][4]

    const int tid  = threadIdx.x;
    const int wv   = tid >> 6;
    const int lane = tid & 63;
    const int q4   = lane >> 4;
    const int l16  = lane & 15;
    const int wr   = wv & 1;
    const int wc   = wv >> 1;     // 0..3
    const int bx   = blockIdx.x;
    const int chunk = bx & 3;     // XCD-affine under round-robin dispatch
    const int R0   = (bx >> 2) * BM;
    const int T0   = chunk * NTILES;

    short8 qfrag[2][16];
    #pragma unroll
    for (int r2 = 0; r2 < 2; ++r2) {
        const unsigned short* qp = Qbf + (size_t)(R0 + wr * 32 + r2 * 16 + l16) * D + q4 * 8;
        #pragma unroll
        for (int kb = 0; kb < 16; ++kb)
            qfrag[r2][kb] = *(const short8*)(qp + kb * 32);
    }

    float tr[2][4];
    #pragma unroll
    for (int r2 = 0; r2 < 2; ++r2)
        #pragma unroll
        for (int ri = 0; ri < 4; ++ri)
            tr[r2][ri] = times[R0 + wr * 32 + r2 * 16 + q4 * 4 + ri];

    float w1v[8], b1v[8], w2v[8];
    #pragma unroll
    for (int k = 0; k < 8; ++k) { w1v[k] = w1[k]; b1v[k] = b1[k]; w2v[k] = w2[k]; }
    const float b2v = b2[0];
    bool fast = true;
    #pragma unroll
    for (int k = 0; k < 8; ++k) fast = fast && (b1v[k] == 0.0f);
    float C1 = 0.0f;
    #pragma unroll
    for (int k = 0; k < 8; ++k) C1 += w2v[k] * fmaxf(w1v[k], 0.0f);

    f32x4 of[2][8];
    #pragma unroll
    for (int r2 = 0; r2 < 2; ++r2)
        #pragma unroll
        for (int dt = 0; dt < 8; ++dt) of[r2][dt] = (f32x4){0.f, 0.f, 0.f, 0.f};
    float lacc[2][4] = {{0.f,0.f,0.f,0.f},{0.f,0.f,0.f,0.f}};

    {
        const unsigned short* src = Kblk + (size_t)T0 * TILE_SH;
        #pragma unroll
        for (int i = 0; i < 8; ++i) {
            int f = wv * 8 + i;
            load_lds16(src + (size_t)f * FRAG_SH + lane * 8, Ks0 + f * FRAG_SH + lane * 8);
        }
    }

    for (int kt = 0; kt < NTILES; ++kt) {
        unsigned short* KsCur = (kt & 1) ? Ks1 : Ks0;
        unsigned short* KsNxt = (kt & 1) ? Ks0 : Ks1;
        const int tglob = T0 + kt;

        __syncthreads();   // KsCur staged; Pb free

        f32x4 c[2] = { {0,0,0,0}, {0,0,0,0} };
        #pragma unroll
        for (int kb = 0; kb < 16; ++kb) {
            short8 b = *(const short8*)(KsCur + (kb * 4 + wc) * FRAG_SH + lane * 8);
            c[0] = __builtin_amdgcn_mfma_f32_16x16x32_bf16(qfrag[0][kb], b, c[0], 0, 0, 0);
            c[1] = __builtin_amdgcn_mfma_f32_16x16x32_bf16(qfrag[1][kb], b, c[1], 0, 0, 0);
        }

        const float tc = times[tglob * BN + wc * 16 + l16];
        #pragma unroll
        for (int r2 = 0; r2 < 2; ++r2) {
            #pragma unroll
            for (int ri = 0; ri < 4; ++ri) {
                float td = fabsf(tr[r2][ri] - tc);
                float a = fmaf(td, C1, b2v);
                if (!fast) {
                    a = b2v;
                    #pragma unroll
                    for (int k = 0; k < 8; ++k)
                        a += w2v[k] * fmaxf(fmaf(td, w1v[k], b1v[k]), 0.f);
                }
                float twt = __builtin_amdgcn_rcpf(1.0f + __expf(-a));
                float s = c[r2][ri] * twt;      // 1/sqrt(D) pre-folded into Q
                float e = __expf(s);
                lacc[r2][ri] += e;
                Pb[(wr * 32 + r2 * 16 + q4 * 4 + ri) * PB_W + wc * 16 + l16] = f2bf_rn(e);
            }
        }
        __syncthreads();   // P visible

        if (kt + 1 < NTILES) {
            const unsigned short* src = Kblk + (size_t)(tglob + 1) * TILE_SH;
            #pragma unroll
            for (int i = 0; i < 8; ++i) {
                int f = wv * 8 + i;
                load_lds16(src + (size_t)f * FRAG_SH + lane * 8, KsNxt + f * FRAG_SH + lane * 8);
            }
        }

        const unsigned short* Vt = Vblk + (size_t)tglob * TILE_SH;
        #pragma unroll
        for (int ks = 0; ks < 2; ++ks) {
            short8 a2[2];
            #pragma unroll
            for (int r2 = 0; r2 < 2; ++r2)
                a2[r2] = *(const short8*)(Pb + ((wr * 2 + r2) * 16 + l16) * PB_W + ks * 32 + q4 * 8);
            #pragma unroll
            for (int dt = 0; dt < 8; ++dt) {
                short8 b = *(const short8*)(Vt + (ks * 32 + wc * 8 + dt) * FRAG_SH + lane * 8);
                of[0][dt] = __builtin_amdgcn_mfma_f32_16x16x32_bf16(a2[0], b, of[0][dt], 0, 0, 0);
                of[1][dt] = __builtin_amdgcn_mfma_f32_16x16x32_bf16(a2[1], b, of[1][dt], 0, 0, 0);
            }
        }
    }

    // ---- denominator partial: butterfly + cross-wave via lred ----
    float lrow[2][4];
    #pragma unroll
    for (int r2 = 0; r2 < 2; ++r2) {
        #pragma unroll
        for (int ri = 0; ri < 4; ++ri) {
            float v = lacc[r2][ri];
            v += __shfl_xor(v, 1);
            v += __shfl_xor(v, 2);
            v += __shfl_xor(v, 4);
            v += __shfl_xor(v, 8);
            lrow[r2][ri] = v;
        }
    }
    if (l16 == 0) {
        #pragma unroll
        for (int r2 = 0; r2 < 2; ++r2)
            #pragma unroll
            for (int ri = 0; ri < 4; ++ri)
                lred[(wr * 32 + r2 * 16 + q4 * 4 + ri) * 4 + wc] = lrow[r2][ri];
    }
    __syncthreads();
    if (tid < BM) {
        float s = lred[tid * 4 + 0] + lred[tid * 4 + 1] + lred[tid * 4 + 2] + lred[tid * 4 + 3];
        if (use_part) dden[(size_t)chunk * N + R0 + tid] = s;
        else          atomicAdd(dden + R0 + tid, s);
    }

    // ---- numerator: plain coalesced stores to per-chunk slab (no RMW) ----
    float* obase = use_part ? (onum + (size_t)chunk * N * D) : onum;
    #pragma unroll
    for (int r2 = 0; r2 < 2; ++r2) {
        #pragma unroll
        for (int ri = 0; ri < 4; ++ri) {
            const int row = R0 + wr * 32 + r2 * 16 + q4 * 4 + ri;
            #pragma unroll
            for (int dt = 0; dt < 8; ++dt) {
                float v = of[r2][dt][ri];
                float* p = obase + (size_t)row * D + wc * 128 + dt * 16 + l16;
                if (use_part) *p = v;
                else          atomicAdd(p, v);
            }
        }
    }
}

// Partial-sum mode: out[i,:] = (sum_s Opart[s][i,:]) / (sum_s dpart[s][i])
__global__ void reduce_normalize_kernel(const float* __restrict__ Opart,
                                        const float* __restrict__ dpart,
                                        float* __restrict__ out) {
    int i = blockIdx.x * 256 + threadIdx.x;   // float4 index
    int row = i >> 7;
    float den = 0.f;
    #pragma unroll
    for (int s = 0; s < KS; ++s) den += dpart[s * N + row];
    float inv = 1.0f / den;
    float4 acc = ((const float4*)Opart)[i];
    #pragma unroll
    for (int s = 1; s < KS; ++s) {
        float4 v = ((const float4*)Opart)[(size_t)s * (N * D / 4) + i];
        acc.x += v.x; acc.y += v.y; acc.z += v.z; acc.w += v.w;
    }
    acc.x *= inv; acc.y *= inv; acc.z *= inv; acc.w *= inv;
    ((float4*)out)[i] = acc;
}

// Atomic-fallback mode: out[i,:] /= denom[i]
__global__ void normalize_kernel(float* __restrict__ out, const float* __restrict__ denom) {
    int i = blockIdx.x * 256 + threadIdx.x;
    int row = i >> 7;
    float inv = 1.0f / denom[row];
    float4 v = ((const float4*)out)[i];
    v.x *= inv; v.y *= inv; v.z *= inv; v.w *= inv;
    ((float4*)out)[i] = v;
}

extern "C" void kernel_launch(void* const* d_in, const int* in_sizes, int n_in,
                              void* d_out, int out_size, void* d_ws, size_t ws_size,
                              hipStream_t stream) {
    const float* q     = (const float*)d_in[0];
    const float* hist  = (const float*)d_in[1];
    const float* times = (const float*)d_in[2];
    const float* w1    = (const float*)d_in[3];
    const float* b1    = (const float*)d_in[4];
    const float* w2    = (const float*)d_in[5];
    const float* b2    = (const float*)d_in[6];
    float* out = (float*)d_out;

    unsigned short* Qbf  = (unsigned short*)d_ws;         // 4 MB
    unsigned short* Kblk = Qbf + (size_t)N * D;           // 4 MB
    unsigned short* Vblk = Kblk + (size_t)N * D;          // 4 MB
    float* Opart = (float*)(Vblk + (size_t)N * D);        // KS * 8 MB = 32 MB
    float* dpart = Opart + (size_t)KS * N * D;            // KS * 16 KB
    const size_t ws_needed = (size_t)3 * N * D * 2
                           + (size_t)KS * N * D * 4 + (size_t)KS * N * 4;
    const int use_part = ws_size >= ws_needed;

    const size_t lds_bytes = (size_t)2 * TILE_SH * 2 + 64 * PB_W * 2 + 64 * 4 * 4;
    hipFuncSetAttribute((const void*)flash_kernel,
                        hipFuncAttributeMaxDynamicSharedMemorySize, 160 * 1024);

    prep_q<<<(N * D) / (256 * 4), 256, 0, stream>>>(q, Qbf);
    prep_kv<<<NKT * 2, 256, 0, stream>>>(hist, Kblk, Vblk);

    if (use_part) {
        flash_kernel<<<N / BM * KS, 512, lds_bytes, stream>>>(
            Qbf, Kblk, Vblk, times, w1, b1, w2, b2, Opart, dpart, 1);
        reduce_normalize_kernel<<<(N * D / 4) / 256, 256, 0, stream>>>(Opart, dpart, out);
    } else {
        float* denom = dpart;   // fits: 16 KB
        hipMemsetAsync(out, 0, (size_t)N * D * sizeof(float), stream);
        hipMemsetAsync(denom, 0, (size_t)N * sizeof(float), stream);
        flash_kernel<<<N / BM * KS, 512, lds_bytes, stream>>>(
            Qbf, Kblk, Vblk, times, w1, b1, w2, b2, out, denom, 0);
        normalize_kernel<<<(N * D / 4) / 256, 256, 0, stream>>>(out, denom);
    }
}